// Round 1
// baseline (553.696 us; speedup 1.0000x reference)
//
#include <hip/hip_runtime.h>
#include <hip/hip_bf16.h>

// MultiheadAttention_ViTNO: B=8, P=256, S=8x8(=64), D=256, NHEAD=8, DK=32, SCALE=64
// Pipeline: k0_prep (weight bf16 + head-permute) -> k1_qkv -> k2a_scores(+softmax)
//           -> k2t_transposeV -> k2b_pv -> k3_out
// All GEMMs: bf16 MFMA 16x16x32, fp32 accum. Barrier-free K-loops, direct global frags.

typedef __bf16 bf16;
typedef __attribute__((ext_vector_type(8))) __bf16 bf16x8;
typedef __attribute__((ext_vector_type(4))) float floatx4;
typedef __attribute__((ext_vector_type(8))) unsigned short ushort8;
typedef __attribute__((ext_vector_type(4))) unsigned int uint4v;

#define T_TOK 131072          // B*P*64 tokens
#define CDIM 2048             // 64*32 flattened (sxy, dk) per head

static __device__ __forceinline__ floatx4 mfma16(bf16x8 a, bf16x8 b, floatx4 c) {
  return __builtin_amdgcn_mfma_f32_16x16x32_bf16(a, b, c, 0, 0, 0);
}

// ---------------- K0: weight prep ----------------
// i' = n*32 + dk  <->  orig i = dk*8 + n  (reference reshape is (dk, nhead))
__global__ __launch_bounds__(256) void k0_prep(
    const float* __restrict__ Wq, const float* __restrict__ bq,
    const float* __restrict__ Wk, const float* __restrict__ bk,
    const float* __restrict__ Wv, const float* __restrict__ bv,
    const float* __restrict__ Wo,
    bf16* __restrict__ WQp, bf16* __restrict__ WKp, bf16* __restrict__ WVp,
    bf16* __restrict__ WOp,
    float* __restrict__ bqp, float* __restrict__ bkp, float* __restrict__ bvp)
{
  int tid = blockIdx.x * 256 + threadIdx.x;   // 0..65535
  int rowp = tid >> 8;                        // i' (for Wq/k/v) or j (for Wo)
  int col  = tid & 255;                       // d (for Wq/k/v) or i' (for Wo)
  int isrc = ((rowp & 31) << 3) | (rowp >> 5);   // orig row for permuted i'
  WQp[tid] = (bf16)Wq[isrc * 256 + col];
  WKp[tid] = (bf16)Wk[isrc * 256 + col];
  WVp[tid] = (bf16)Wv[isrc * 256 + col];
  int i2src = ((col & 31) << 3) | (col >> 5);    // orig col for permuted i'
  WOp[tid] = (bf16)Wo[rowp * 256 + i2src];
  if (tid < 256) {
    int bs = ((tid & 31) << 3) | (tid >> 5);
    bqp[tid] = bq[bs]; bkp[tid] = bk[bs]; bvp[tid] = bv[bs];
  }
}

// ---------------- K1: QKV projection ----------------
// grid (2048, 3); block 256. Out: Qh/Kh/Vh[bn=b*8+n][p][c=sxy*32+dk] bf16.
__global__ __launch_bounds__(256) void k1_qkv(
    const float* __restrict__ x,
    const bf16* __restrict__ Wq, const bf16* __restrict__ Wk, const bf16* __restrict__ Wv,
    const float* __restrict__ bq, const float* __restrict__ bk, const float* __restrict__ bv,
    bf16* __restrict__ Qh, bf16* __restrict__ Kh, bf16* __restrict__ Vh)
{
  const int mat = blockIdx.y;
  const bf16*  W    = (mat == 0) ? Wq : (mat == 1) ? Wk : Wv;
  const float* bias = (mat == 0) ? bq : (mat == 1) ? bk : bv;
  bf16*        out  = (mat == 0) ? Qh : (mat == 1) ? Kh : Vh;

  const int t0 = blockIdx.x * 64;
  const int lane = threadIdx.x & 63;
  const int wv = threadIdx.x >> 6;     // wave 0..3 -> col quadrant
  const int h  = lane >> 4;            // 0..3
  const int cl = lane & 15;

  floatx4 acc[4][4];
#pragma unroll
  for (int i = 0; i < 4; i++)
#pragma unroll
    for (int j = 0; j < 4; j++) acc[i][j] = (floatx4)0.0f;

  for (int k0 = 0; k0 < 256; k0 += 32) {
    bf16x8 a[4];
#pragma unroll
    for (int mt = 0; mt < 4; mt++) {
      const float* xp = x + (size_t)(t0 + mt * 16 + cl) * 256 + k0 + 8 * h;
      floatx4 f0 = *reinterpret_cast<const floatx4*>(xp);
      floatx4 f1 = *reinterpret_cast<const floatx4*>(xp + 4);
      bf16x8 av;
#pragma unroll
      for (int j = 0; j < 4; j++) { av[j] = (bf16)f0[j]; av[4 + j] = (bf16)f1[j]; }
      a[mt] = av;
    }
#pragma unroll
    for (int nt = 0; nt < 4; nt++) {
      const bf16* wp = W + (size_t)(64 * wv + nt * 16 + cl) * 256 + k0 + 8 * h;
      bf16x8 b8 = *reinterpret_cast<const bf16x8*>(wp);
#pragma unroll
      for (int mt = 0; mt < 4; mt++) acc[mt][nt] = mfma16(a[mt], b8, acc[mt][nt]);
    }
  }

  const int b = t0 >> 14;
  const int p = (t0 >> 6) & 255;
#pragma unroll
  for (int nt = 0; nt < 4; nt++) {
    const int ip = 64 * wv + nt * 16 + cl;     // i' = n*32+dk
    const int n = ip >> 5, dk = ip & 31;
    const float bb = bias[ip];
    bf16* ob = out + ((size_t)((b * 8 + n) * 256 + p)) * CDIM + dk;
#pragma unroll
    for (int mt = 0; mt < 4; mt++)
#pragma unroll
      for (int r = 0; r < 4; r++) {
        int sxy = mt * 16 + 4 * h + r;
        ob[sxy * 32] = (bf16)(acc[mt][nt][r] + bb);
      }
  }
}

// ---------------- K2a: scores + softmax ----------------
// grid 256 (= 64 bn * 4 ptiles); block 256. attn[bn][p][q] bf16.
__global__ __launch_bounds__(256) void k2a_scores(
    const bf16* __restrict__ Qh, const bf16* __restrict__ Kh,
    bf16* __restrict__ attn)
{
  const int bx = blockIdx.x;
  const int bn = bx >> 2;
  const int p0 = (bx & 3) * 64;
  const int lane = threadIdx.x & 63;
  const int wv = threadIdx.x >> 6;
  const int h = lane >> 4, cl = lane & 15;

  const bf16* Qb = Qh + (size_t)bn * 256 * CDIM;
  const bf16* Kb = Kh + (size_t)bn * 256 * CDIM;

  floatx4 acc[4][4];
#pragma unroll
  for (int i = 0; i < 4; i++)
#pragma unroll
    for (int j = 0; j < 4; j++) acc[i][j] = (floatx4)0.0f;

#pragma unroll 2
  for (int k0 = 0; k0 < CDIM; k0 += 32) {
    bf16x8 a[4], bb[4];
#pragma unroll
    for (int mt = 0; mt < 4; mt++)
      a[mt] = *reinterpret_cast<const bf16x8*>(Qb + (size_t)(p0 + mt * 16 + cl) * CDIM + k0 + 8 * h);
#pragma unroll
    for (int nt = 0; nt < 4; nt++)
      bb[nt] = *reinterpret_cast<const bf16x8*>(Kb + (size_t)(64 * wv + nt * 16 + cl) * CDIM + k0 + 8 * h);
#pragma unroll
    for (int nt = 0; nt < 4; nt++)
#pragma unroll
      for (int mt = 0; mt < 4; mt++) acc[mt][nt] = mfma16(a[mt], bb[nt], acc[mt][nt]);
  }

  // softmax over q (scores = raw/64). Rows held: mt*16 + 4h + r. Cols: 64*wv + nt*16 + cl.
  __shared__ float redmax[4][64];
  __shared__ float redsum[4][64];

  float pm[4][4];
#pragma unroll
  for (int mt = 0; mt < 4; mt++)
#pragma unroll
    for (int r = 0; r < 4; r++) {
      float m = fmaxf(fmaxf(acc[mt][0][r], acc[mt][1][r]), fmaxf(acc[mt][2][r], acc[mt][3][r]));
      pm[mt][r] = m;
    }
#pragma unroll
  for (int off = 1; off < 16; off <<= 1)
#pragma unroll
    for (int mt = 0; mt < 4; mt++)
#pragma unroll
      for (int r = 0; r < 4; r++)
        pm[mt][r] = fmaxf(pm[mt][r], __shfl_xor(pm[mt][r], off, 64));
  if (cl == 0) {
#pragma unroll
    for (int mt = 0; mt < 4; mt++)
#pragma unroll
      for (int r = 0; r < 4; r++) redmax[wv][mt * 16 + 4 * h + r] = pm[mt][r];
  }
  __syncthreads();

  float gm[4][4], ps[4][4];
#pragma unroll
  for (int mt = 0; mt < 4; mt++)
#pragma unroll
    for (int r = 0; r < 4; r++) {
      int row = mt * 16 + 4 * h + r;
      gm[mt][r] = fmaxf(fmaxf(redmax[0][row], redmax[1][row]),
                        fmaxf(redmax[2][row], redmax[3][row]));
      ps[mt][r] = 0.0f;
    }
  const float KS = 1.44269504088896340736f / 64.0f;   // log2(e)/SCALE
#pragma unroll
  for (int mt = 0; mt < 4; mt++)
#pragma unroll
    for (int nt = 0; nt < 4; nt++)
#pragma unroll
      for (int r = 0; r < 4; r++) {
        float e = exp2f((acc[mt][nt][r] - gm[mt][r]) * KS);
        acc[mt][nt][r] = e;
        ps[mt][r] += e;
      }
#pragma unroll
  for (int off = 1; off < 16; off <<= 1)
#pragma unroll
    for (int mt = 0; mt < 4; mt++)
#pragma unroll
      for (int r = 0; r < 4; r++) ps[mt][r] += __shfl_xor(ps[mt][r], off, 64);
  if (cl == 0) {
#pragma unroll
    for (int mt = 0; mt < 4; mt++)
#pragma unroll
      for (int r = 0; r < 4; r++) redsum[wv][mt * 16 + 4 * h + r] = ps[mt][r];
  }
  __syncthreads();

#pragma unroll
  for (int mt = 0; mt < 4; mt++)
#pragma unroll
    for (int r = 0; r < 4; r++) {
      int row = mt * 16 + 4 * h + r;
      float gs = redsum[0][row] + redsum[1][row] + redsum[2][row] + redsum[3][row];
      ps[mt][r] = 1.0f / gs;   // reuse as inv-sum
    }
#pragma unroll
  for (int nt = 0; nt < 4; nt++) {
    int q = 64 * wv + nt * 16 + cl;
#pragma unroll
    for (int mt = 0; mt < 4; mt++)
#pragma unroll
      for (int r = 0; r < 4; r++) {
        int row = p0 + mt * 16 + 4 * h + r;
        attn[(size_t)bn * 65536 + row * 256 + q] = (bf16)(acc[mt][nt][r] * ps[mt][r]);
      }
  }
}

// ---------------- K2t: V transpose (Vh[bn][q][c] -> Vt[bn][c][q]) ----------------
// grid 8192 (= 64 bn * 4 qtiles * 32 ctiles); block 256. LDS [64][65] pad: 2-way only.
__global__ __launch_bounds__(256) void k2t_transpose(
    const bf16* __restrict__ Vh, bf16* __restrict__ Vt)
{
  const int bx = blockIdx.x;
  const int bn = bx >> 7;
  const int q0 = ((bx >> 5) & 3) * 64;
  const int c0 = (bx & 31) * 64;
  __shared__ unsigned short tile[64][65];
  const unsigned short* src = (const unsigned short*)Vh + (size_t)bn * 524288;
  unsigned short* dst = (unsigned short*)Vt + (size_t)bn * 524288;
  {
    const int q = threadIdx.x >> 3;            // 0..31
    const int cj = (threadIdx.x & 7) * 8;
#pragma unroll
    for (int it = 0; it < 2; ++it) {
      int qq = q + it * 32;
      ushort8 s = *reinterpret_cast<const ushort8*>(src + (size_t)(q0 + qq) * CDIM + c0 + cj);
#pragma unroll
      for (int j = 0; j < 8; j++) tile[qq][cj + j] = s[j];
    }
  }
  __syncthreads();
  {
    const int crow = threadIdx.x >> 2;         // 0..63
    const int qj = (threadIdx.x & 3) * 8;
#pragma unroll
    for (int it = 0; it < 2; ++it) {
      int qq = qj + it * 32;
      ushort8 sv;
#pragma unroll
      for (int j = 0; j < 8; j++) sv[j] = tile[qq + j][crow];
      *reinterpret_cast<ushort8*>(dst + (size_t)(c0 + crow) * 256 + q0 + qq) = sv;
    }
  }
}

// ---------------- K2b: O = attn @ V ----------------
// grid 2048 (= 64 bn * 4 ptiles * 8 ctiles); block 256. yhat[t][i'=n*32+dk] bf16.
__global__ __launch_bounds__(256) void k2b_pv(
    const bf16* __restrict__ attn, const bf16* __restrict__ Vt,
    bf16* __restrict__ yhat)
{
  const int bx = blockIdx.x;
  const int bn = bx >> 5;
  const int p0 = ((bx >> 3) & 3) * 64;
  const int c0 = (bx & 7) * 256;
  const int lane = threadIdx.x & 63;
  const int wv = threadIdx.x >> 6;
  const int h = lane >> 4, cl = lane & 15;

  const bf16* Ab = attn + (size_t)bn * 65536;
  const bf16* Vb = Vt + (size_t)bn * 524288;

  floatx4 acc[4][4];
#pragma unroll
  for (int i = 0; i < 4; i++)
#pragma unroll
    for (int j = 0; j < 4; j++) acc[i][j] = (floatx4)0.0f;

  for (int q0 = 0; q0 < 256; q0 += 32) {
    bf16x8 a[4];
#pragma unroll
    for (int mt = 0; mt < 4; mt++)
      a[mt] = *reinterpret_cast<const bf16x8*>(Ab + (size_t)(p0 + mt * 16 + cl) * 256 + q0 + 8 * h);
#pragma unroll
    for (int nt = 0; nt < 4; nt++) {
      bf16x8 b8 = *reinterpret_cast<const bf16x8*>(Vb + (size_t)(c0 + 64 * wv + nt * 16 + cl) * 256 + q0 + 8 * h);
#pragma unroll
      for (int mt = 0; mt < 4; mt++) acc[mt][nt] = mfma16(a[mt], b8, acc[mt][nt]);
    }
  }

  const int b = bn >> 3, n = bn & 7;
#pragma unroll
  for (int nt = 0; nt < 4; nt++) {
    const int cg = c0 + 64 * wv + nt * 16 + cl;
    const int dk = cg & 31, sxy = cg >> 5;
#pragma unroll
    for (int mt = 0; mt < 4; mt++)
#pragma unroll
      for (int r = 0; r < 4; r++) {
        int p = p0 + mt * 16 + 4 * h + r;
        size_t t = (size_t)(b * 256 + p) * 64 + sxy;
        yhat[t * 256 + n * 32 + dk] = (bf16)acc[mt][nt][r];
      }
  }
}

// ---------------- K3: output projection ----------------
// grid 2048; block 256. out[t][j] fp32 = yhat[t][:] . WOp[j][:] + bo[j]
__global__ __launch_bounds__(256) void k3_out(
    const bf16* __restrict__ yhat, const bf16* __restrict__ Wo,
    const float* __restrict__ bo, float* __restrict__ outp)
{
  const int t0 = blockIdx.x * 64;
  const int lane = threadIdx.x & 63;
  const int wv = threadIdx.x >> 6;
  const int h = lane >> 4, cl = lane & 15;

  floatx4 acc[4][4];
#pragma unroll
  for (int i = 0; i < 4; i++)
#pragma unroll
    for (int j = 0; j < 4; j++) acc[i][j] = (floatx4)0.0f;

  for (int k0 = 0; k0 < 256; k0 += 32) {
    bf16x8 a[4];
#pragma unroll
    for (int mt = 0; mt < 4; mt++)
      a[mt] = *reinterpret_cast<const bf16x8*>(yhat + (size_t)(t0 + mt * 16 + cl) * 256 + k0 + 8 * h);
#pragma unroll
    for (int nt = 0; nt < 4; nt++) {
      bf16x8 b8 = *reinterpret_cast<const bf16x8*>(Wo + (size_t)(64 * wv + nt * 16 + cl) * 256 + k0 + 8 * h);
#pragma unroll
      for (int mt = 0; mt < 4; mt++) acc[mt][nt] = mfma16(a[mt], b8, acc[mt][nt]);
    }
  }

#pragma unroll
  for (int nt = 0; nt < 4; nt++) {
    const int j = 64 * wv + nt * 16 + cl;
    const float bb = bo[j];
#pragma unroll
    for (int mt = 0; mt < 4; mt++)
#pragma unroll
      for (int r = 0; r < 4; r++)
        outp[(size_t)(t0 + mt * 16 + 4 * h + r) * 256 + j] = acc[mt][nt][r] + bb;
  }
}

// ---------------- launch ----------------
extern "C" void kernel_launch(void* const* d_in, const int* in_sizes, int n_in,
                              void* d_out, int out_size, void* d_ws, size_t ws_size,
                              hipStream_t stream) {
  const float* x  = (const float*)d_in[0];
  const float* Wq = (const float*)d_in[1];
  const float* bq = (const float*)d_in[2];
  const float* Wk = (const float*)d_in[3];
  const float* bk = (const float*)d_in[4];
  const float* Wv = (const float*)d_in[5];
  const float* bv = (const float*)d_in[6];
  const float* Wo = (const float*)d_in[7];
  const float* bo = (const float*)d_in[8];
  float* outp = (float*)d_out;

  char* ws = (char*)d_ws;
  const size_t SZ_QKV = 67108864;   // 64*256*2048 * 2B
  size_t off = 0;
  bf16* Qh   = (bf16*)(ws + off); off += SZ_QKV;
  bf16* Kh   = (bf16*)(ws + off); off += SZ_QKV;
  bf16* Vh   = (bf16*)(ws + off); off += SZ_QKV;
  bf16* attn = (bf16*)(ws + off); off += 8388608;
  bf16* WQp  = (bf16*)(ws + off); off += 131072;
  bf16* WKp  = (bf16*)(ws + off); off += 131072;
  bf16* WVp  = (bf16*)(ws + off); off += 131072;
  bf16* WOp  = (bf16*)(ws + off); off += 131072;
  float* bqp = (float*)(ws + off); off += 1024;
  float* bkp = (float*)(ws + off); off += 1024;
  float* bvp = (float*)(ws + off); off += 1024;
  if (ws_size < off) return;        // workspace too small: bail cleanly

  bf16* yhat = Qh;                  // Qh dead after k2a
  bf16* Vt   = Kh;                  // Kh dead after k2a

  k0_prep<<<256, 256, 0, stream>>>(Wq, bq, Wk, bk, Wv, bv, Wo,
                                   WQp, WKp, WVp, WOp, bqp, bkp, bvp);
  k1_qkv<<<dim3(2048, 3), 256, 0, stream>>>(x, WQp, WKp, WVp, bqp, bkp, bvp, Qh, Kh, Vh);
  k2a_scores<<<256, 256, 0, stream>>>(Qh, Kh, attn);
  k2t_transpose<<<8192, 256, 0, stream>>>(Vh, Vt);
  k2b_pv<<<2048, 256, 0, stream>>>(attn, Vt, yhat);
  k3_out<<<2048, 256, 0, stream>>>(yhat, WOp, bo, outp);
}